// Round 20
// baseline (74.996 us; speedup 1.0000x reference)
//
#include <hip/hip_runtime.h>

typedef unsigned short u16;
typedef unsigned int u32;
typedef __attribute__((ext_vector_type(8))) __bf16 bf16x8;
typedef __attribute__((ext_vector_type(4))) float f32x4;

// RK2 midpoint, single step h = 1:  k1=f(z); k2=f(z + k1/2); y = z + k2
// tanh input pre-scale folded into GEMM1-path weights: acc = 2*log2(e)*(zu@W1+b1)
constexpr float TSC = 2.885390081777927f;   // 2*log2(e)

// weight regions, u16 units. All A-frags 16x16x32: lane l holds
// A[m = base+(l&15)][k = kc*32 + (l>>4)*8 + e].
// Global K layout: z(64) | u(16) 1(1) pad(15) | H(...)
#define OFF_WG1   0        // [16 ct][3 kc]  f: W1 (K=96: z|u|b1-ones)   (24576)
#define OFF_WG2   24576    // [4 ct][11 kc]  f: A^T,c2-ones,W2 (K=352)   (22528)
#define OFF_WH1   47104    // [8 ct][3 kc]   head L1 (K=96)              (12288)
#define OFF_WH2   59392    // [2 ot][5 kc]   head L2 (K=128 H | ob2-ones)(5120)
#define W_TOTAL   64512

// X2 row stride (elems): padded linear. 328*2B = 656 B -> row r starts at
// bank 4r mod 32; all LDS addresses fold to base + compile-time immediates.
#define XS 328

__device__ __forceinline__ u16 f2bf(float f) {
  __bf16 h = (__bf16)f;
  return __builtin_bit_cast(u16, h);
}
__device__ __forceinline__ u32 pk2(float a, float b) {
  return (u32)f2bf(a) | ((u32)f2bf(b) << 16);
}
// input already scaled by 2*log2(e): tanh = 1 - 2/(2^x + 1)
__device__ __forceinline__ float tanh_pre(float x) {
#if __has_builtin(__builtin_amdgcn_exp2f)
  float e = __builtin_amdgcn_exp2f(x);
#else
  float e = exp2f(x);
#endif
  return 1.0f - 2.0f * __builtin_amdgcn_rcpf(e + 1.0f);
}

// ---------------- setup: pack weights as 16x16x32 A-frags --------------------
__global__ void setup_kernel(const float* __restrict__ L,
  const float* __restrict__ aw1, const float* __restrict__ ab1,
  const float* __restrict__ aw2, const float* __restrict__ ab2,
  const float* __restrict__ rw1, const float* __restrict__ rb1,
  const float* __restrict__ rw2, const float* __restrict__ rb2,
  const float* __restrict__ ow1, const float* __restrict__ ob1,
  const float* __restrict__ ow2, const float* __restrict__ ob2,
  u16* __restrict__ W)
{
  const int gid = blockIdx.x * blockDim.x + threadIdx.x;
  const int gstr = gridDim.x * blockDim.x;
  for (int i = gid; i < W_TOTAL; i += gstr) {
    float v;
    if (i < 24576) {                 // Wg1: hidden 256 x K=96, TSC-scaled
      const int j = i, e = j & 7, l = (j >> 3) & 63, f = j >> 9;
      const int ct = f / 3, kc = f - ct * 3;
      const int m = ct * 16 + (l & 15);
      const int k = kc * 32 + ((l >> 4) << 3) + e;
      if (k < 64)       v = TSC * ((m < 128) ? aw1[m * 80 + k] : rw1[(m - 128) * 80 + k]);
      else if (k < 80)  v = TSC * ((m < 128) ? aw1[m * 80 + 64 + (k - 64)]
                                             : rw1[(m - 128) * 80 + 64 + (k - 64)]);
      else if (k == 80) v = TSC * ((m < 128) ? ab1[m] : rb1[m - 128]);
      else              v = 0.0f;
    } else if (i < 47104) {          // Wg2: lat 64 x K=352 (z:A^T | c2-ones | H:w2)
      const int j = i - 24576, e = j & 7, l = (j >> 3) & 63, f = j >> 9;
      const int ct = f / 11, kc = f - ct * 11;
      const int m = ct * 16 + (l & 15);
      const int k = kc * 32 + ((l >> 4) << 3) + e;
      if (k < 64) {                  // A = -(L L^T), symmetric
        float s = 0.0f;
        for (int q = 0; q < 64; ++q) s += L[m * 64 + q] * L[k * 64 + q];
        v = -s;
      } else if (k == 80) v = ab2[m] + rb2[m];
      else if (k < 96)    v = 0.0f;
      else {
        const int h = k - 96;
        v = (h < 128) ? aw2[m * 128 + h] : rw2[m * 128 + (h - 128)];
      }
    } else if (i < 59392) {          // Wh1: head hidden 128 x K=96 (unscaled)
      const int j = i - 47104, e = j & 7, l = (j >> 3) & 63, f = j >> 9;
      const int ct = f / 3, kc = f - ct * 3;
      const int m = ct * 16 + (l & 15);
      const int k = kc * 32 + ((l >> 4) << 3) + e;
      if (k < 64)       v = ow1[m * 80 + k];
      else if (k < 80)  v = ow1[m * 80 + 64 + (k - 64)];
      else if (k == 80) v = ob1[m];
      else              v = 0.0f;
    } else {                         // Wh2: out 32(pad of 20) x K=160 (H | ob2-ones)
      const int j = i - 59392, e = j & 7, l = (j >> 3) & 63, f = j >> 9;
      const int ot = f / 5, kc = f - ot * 5;
      const int m = ot * 16 + (l & 15);
      const int k = kc * 32 + ((l >> 4) << 3) + e;
      if (m >= 20)       v = 0.0f;
      else if (k < 128)  v = ow2[m * 128 + k];
      else if (k == 144) v = ob2[m];
      else               v = 0.0f;
    }
    W[i] = f2bf(v);
  }
}

// ---------------- fused: RK2 step (2 fevals) + head ---------------------------
// R20 = R18 + GEMM2's z/u K-chunks (kc 0,1,2) moved into phase A: z-frags are
// already live there, the 3 weights load before the barrier, and the 6 extra
// MFMAs overlap the tanh chain. Phase B shrinks to the 8 H-chunks. Only acc2
// (8 regs) is held across the barrier; everything else matches R18.
__global__ __launch_bounds__(256, 2) void fused_kernel(
    const float* __restrict__ zt, const float* __restrict__ ut,
    const u16* __restrict__ W,
    float* __restrict__ outz, float* __restrict__ outy)
{
  __shared__ __align__(16) u16 X2[32 * XS];    // [z(64)|u-gap|H(256)] bf16
  __shared__ const u16* WpS;                   // opaque weight base (anti-LICM)
  const int tid = threadIdx.x, w = tid >> 6, l = tid & 63, li = l & 15, h4 = l >> 4;
  const int R0 = blockIdx.x * 32;
  const int latb = w * 16 + 4 * h4;            // owned 4 lat cols

  if (tid == 0) WpS = W;

  // per-thread LDS bases (elems)
  const int rb0 = li * XS;                     // row li
  const int rb1b = (16 + li) * XS;             // row 16+li

  // ---- stage X2 z (full tile, thread-strided) ----
  {
    const int r = tid >> 3, c0 = (tid & 7) * 8;
    const float4 za = *(const float4*)&zt[(size_t)(R0 + r) * 64 + c0];
    const float4 zb = *(const float4*)&zt[(size_t)(R0 + r) * 64 + c0 + 4];
    *(uint4*)&X2[r * XS + c0] =
        make_uint4(pk2(za.x, za.y), pk2(za.z, za.w), pk2(zb.x, zb.y), pk2(zb.z, zb.w));
  }
  // ---- z8 state (owned positions) ----
  float z8[8];
  {
    const float4 a = *(const float4*)&zt[(size_t)(R0 + li) * 64 + latb];
    const float4 b = *(const float4*)&zt[(size_t)(R0 + 16 + li) * 64 + latb];
    z8[0] = a.x; z8[1] = a.y; z8[2] = a.z; z8[3] = a.w;
    z8[4] = b.x; z8[5] = b.y; z8[6] = b.z; z8[7] = b.w;
  }
  // ---- bu[rt]: resident B-frags holding u(16)|1|pad for K-slice 64..95 ----
  bf16x8 bu[2];
  #pragma unroll
  for (int rt = 0; rt < 2; ++rt) {
    union { bf16x8 v; uint4 u; } t;
    if (h4 < 2) {
      const float4 ua = *(const float4*)&ut[(size_t)(R0 + rt * 16 + li) * 16 + h4 * 8];
      const float4 ub = *(const float4*)&ut[(size_t)(R0 + rt * 16 + li) * 16 + h4 * 8 + 4];
      t.u = make_uint4(pk2(ua.x, ua.y), pk2(ua.z, ua.w), pk2(ub.x, ub.y), pk2(ub.z, ub.w));
    } else if (h4 == 2) {
      t.u = make_uint4(0x3F80u, 0u, 0u, 0u);   // {1, 0, ...} at k_local 16 (k=80)
    } else {
      t.u = make_uint4(0u, 0u, 0u, 0u);
    }
    bu[rt] = t.v;
  }

  float kp8[8];

  auto feval = [&]() {
    const u16* Wp = WpS;                      // opaque: reload weights each call
    // GEMM2 z/u weights (kc 0..2): no X2 dependency -> load before the barrier
    bf16x8 wz0 = *(const bf16x8*)(Wp + OFF_WG2 + ((w * 11 + 0) * 64 + l) * 8);
    bf16x8 wz1 = *(const bf16x8*)(Wp + OFF_WG2 + ((w * 11 + 1) * 64 + l) * 8);
    bf16x8 wz2 = *(const bf16x8*)(Wp + OFF_WG2 + ((w * 11 + 2) * 64 + l) * 8);
    __syncthreads();                          // zi (+WpS first time) visible
    f32x4 acc2[2];                            // GEMM2 partial, carried over barrier
    {
      bf16x8 bz[2][2];
      #pragma unroll
      for (int rt = 0; rt < 2; ++rt) {
        const int rb = rt ? rb1b : rb0;
        bz[rt][0] = *(const bf16x8*)&X2[rb + h4 * 8];
        bz[rt][1] = *(const bf16x8*)&X2[rb + 32 + h4 * 8];
      }
      // GEMM2 z/u-part (6 MFMAs, independent of GEMM1 -> overlaps tanh)
      #pragma unroll
      for (int rt = 0; rt < 2; ++rt) {
        f32x4 a = {0.0f, 0.0f, 0.0f, 0.0f};
        a = __builtin_amdgcn_mfma_f32_16x16x32_bf16(wz0, bz[rt][0], a, 0, 0, 0);
        a = __builtin_amdgcn_mfma_f32_16x16x32_bf16(wz1, bz[rt][1], a, 0, 0, 0);
        a = __builtin_amdgcn_mfma_f32_16x16x32_bf16(wz2, bu[rt],   a, 0, 0, 0);
        acc2[rt] = a;
      }
      // GEMM1: H = tanh(z@W1z + u@W1u + b1)
      #pragma unroll
      for (int ct = 0; ct < 4; ++ct) {
        const int cg = w * 4 + ct;
        const bf16x8 w0 = *(const bf16x8*)(Wp + OFF_WG1 + ((cg * 3 + 0) * 64 + l) * 8);
        const bf16x8 w1 = *(const bf16x8*)(Wp + OFF_WG1 + ((cg * 3 + 1) * 64 + l) * 8);
        const bf16x8 w2 = *(const bf16x8*)(Wp + OFF_WG1 + ((cg * 3 + 2) * 64 + l) * 8);
        const int hcb = 64 + cg * 16 + 4 * h4;
        #pragma unroll
        for (int rt = 0; rt < 2; ++rt) {
          f32x4 acc = {0.0f, 0.0f, 0.0f, 0.0f};
          acc = __builtin_amdgcn_mfma_f32_16x16x32_bf16(w0, bz[rt][0], acc, 0, 0, 0);
          acc = __builtin_amdgcn_mfma_f32_16x16x32_bf16(w1, bz[rt][1], acc, 0, 0, 0);
          acc = __builtin_amdgcn_mfma_f32_16x16x32_bf16(w2, bu[rt],   acc, 0, 0, 0);
          const float t0 = tanh_pre(acc[0]), t1 = tanh_pre(acc[1]);
          const float t2 = tanh_pre(acc[2]), t3 = tanh_pre(acc[3]);
          *(uint2*)&X2[(rt ? rb1b : rb0) + hcb] = make_uint2(pk2(t0, t1), pk2(t2, t3));
        }
      }
    }
    __syncthreads();                          // H visible
    // GEMM2 H-part: 8 kc chunks, single chain per rt (2 indep chains via rt)
    #pragma unroll
    for (int kc = 3; kc < 11; ++kc) {
      const bf16x8 wk = *(const bf16x8*)(Wp + OFF_WG2 + ((w * 11 + kc) * 64 + l) * 8);
      #pragma unroll
      for (int rt = 0; rt < 2; ++rt) {
        const bf16x8 bf =
            *(const bf16x8*)&X2[(rt ? rb1b : rb0) + 64 + (kc - 3) * 32 + h4 * 8];
        acc2[rt] = __builtin_amdgcn_mfma_f32_16x16x32_bf16(wk, bf, acc2[rt], 0, 0, 0);
      }
    }
    #pragma unroll
    for (int rt = 0; rt < 2; ++rt)
      #pragma unroll
      for (int r = 0; r < 4; ++r) kp8[rt * 4 + r] = acc2[rt][r];
  };

  auto stzi = [&](const float* v) {
    *(uint2*)&X2[rb0 + latb]  = make_uint2(pk2(v[0], v[1]), pk2(v[2], v[3]));
    *(uint2*)&X2[rb1b + latb] = make_uint2(pk2(v[4], v[5]), pk2(v[6], v[7]));
  };

  // RK2 midpoint; weights reloaded per iteration (unroll 1 keeps them dead)
  #pragma unroll 1
  for (int s = 0; s < 2; ++s) {
    feval();
    if (s == 0) {
      #pragma unroll
      for (int i = 0; i < 8; ++i) kp8[i] = z8[i] + 0.5f * kp8[i];
      stzi(kp8);
    }
  }
  #pragma unroll
  for (int i = 0; i < 8; ++i) z8[i] += kp8[i];
  stzi(z8);                                    // z_final -> X2 (bf16) for head
  // zt1 out (f32 from regs)
  *(float4*)&outz[(size_t)(R0 + li) * 64 + latb]      = make_float4(z8[0], z8[1], z8[2], z8[3]);
  *(float4*)&outz[(size_t)(R0 + 16 + li) * 64 + latb] = make_float4(z8[4], z8[5], z8[6], z8[7]);

  // ---------------- output head ----------------
  __syncthreads();                             // z_final visible; k2 reads done
  {
    const u16* Wp = WpS;
    bf16x8 bzf[2][2];
    #pragma unroll
    for (int rt = 0; rt < 2; ++rt) {
      const int rb = rt ? rb1b : rb0;
      bzf[rt][0] = *(const bf16x8*)&X2[rb + h4 * 8];
      bzf[rt][1] = *(const bf16x8*)&X2[rb + 32 + h4 * 8];
    }
    // head GEMM1: relu(z@Wh1 + u@Wh1u + ob1) -> X2 H cols [64,192)
    #pragma unroll
    for (int j2 = 0; j2 < 2; ++j2) {
      const int cg = w * 2 + j2;
      const bf16x8 w0 = *(const bf16x8*)(Wp + OFF_WH1 + ((cg * 3 + 0) * 64 + l) * 8);
      const bf16x8 w1 = *(const bf16x8*)(Wp + OFF_WH1 + ((cg * 3 + 1) * 64 + l) * 8);
      const bf16x8 w2 = *(const bf16x8*)(Wp + OFF_WH1 + ((cg * 3 + 2) * 64 + l) * 8);
      const int hcb = 64 + cg * 16 + 4 * h4;
      #pragma unroll
      for (int rt = 0; rt < 2; ++rt) {
        f32x4 acc = {0.0f, 0.0f, 0.0f, 0.0f};
        acc = __builtin_amdgcn_mfma_f32_16x16x32_bf16(w0, bzf[rt][0], acc, 0, 0, 0);
        acc = __builtin_amdgcn_mfma_f32_16x16x32_bf16(w1, bzf[rt][1], acc, 0, 0, 0);
        acc = __builtin_amdgcn_mfma_f32_16x16x32_bf16(w2, bu[rt],    acc, 0, 0, 0);
        const float e0 = fmaxf(acc[0], 0.0f), e1 = fmaxf(acc[1], 0.0f);
        const float e2 = fmaxf(acc[2], 0.0f), e3 = fmaxf(acc[3], 0.0f);
        *(uint2*)&X2[(rt ? rb1b : rb0) + hcb] = make_uint2(pk2(e0, e1), pk2(e2, e3));
      }
    }
  }
  __syncthreads();
  // head GEMM2: waves 0,1 -> 20 output cols (pad 32); bias via bu ones-col
  if (w < 2) {
    const u16* Wp = WpS;
    const int ocb = w * 16 + 4 * h4;
    f32x4 acco[2] = {{0.0f, 0.0f, 0.0f, 0.0f}, {0.0f, 0.0f, 0.0f, 0.0f}};
    #pragma unroll
    for (int kc = 0; kc < 4; ++kc) {
      const bf16x8 wk = *(const bf16x8*)(Wp + OFF_WH2 + ((w * 5 + kc) * 64 + l) * 8);
      #pragma unroll
      for (int rt = 0; rt < 2; ++rt) {
        const bf16x8 bh = *(const bf16x8*)&X2[(rt ? rb1b : rb0) + 64 + kc * 32 + h4 * 8];
        acco[rt] = __builtin_amdgcn_mfma_f32_16x16x32_bf16(wk, bh, acco[rt], 0, 0, 0);
      }
    }
    {
      const bf16x8 wb = *(const bf16x8*)(Wp + OFF_WH2 + ((w * 5 + 4) * 64 + l) * 8);
      #pragma unroll
      for (int rt = 0; rt < 2; ++rt)
        acco[rt] = __builtin_amdgcn_mfma_f32_16x16x32_bf16(wb, bu[rt], acco[rt], 0, 0, 0);
    }
    if (ocb < 20) {
      *(float4*)&outy[(size_t)(R0 + li) * 20 + ocb] =
          make_float4(acco[0][0], acco[0][1], acco[0][2], acco[0][3]);
      *(float4*)&outy[(size_t)(R0 + 16 + li) * 20 + ocb] =
          make_float4(acco[1][0], acco[1][1], acco[1][2], acco[1][3]);
    }
  }
}

extern "C" void kernel_launch(void* const* d_in, const int* in_sizes, int n_in,
                              void* d_out, int out_size, void* d_ws, size_t ws_size,
                              hipStream_t stream) {
  const float* zt  = (const float*)d_in[0];
  const float* ut  = (const float*)d_in[2];
  const float* L   = (const float*)d_in[3];
  const float* aw1 = (const float*)d_in[4];
  const float* ab1 = (const float*)d_in[5];
  const float* aw2 = (const float*)d_in[6];
  const float* ab2 = (const float*)d_in[7];
  const float* rw1 = (const float*)d_in[8];
  const float* rb1 = (const float*)d_in[9];
  const float* rw2 = (const float*)d_in[10];
  const float* rb2 = (const float*)d_in[11];
  const float* ow1 = (const float*)d_in[12];
  const float* ob1 = (const float*)d_in[13];
  const float* ow2 = (const float*)d_in[14];
  const float* ob2 = (const float*)d_in[15];

  u16* W = (u16*)d_ws;
  float* outz = (float*)d_out;
  float* outy = outz + (size_t)131072 * 64;

  hipLaunchKernelGGL(setup_kernel, dim3(64), dim3(256), 0, stream,
      L, aw1, ab1, aw2, ab2, rw1, rb1, rw2, rb2, ow1, ob1, ow2, ob2, W);
  hipLaunchKernelGGL(fused_kernel, dim3(4096), dim3(256), 0, stream,
      zt, ut, W, outz, outy);
}

// Round 21
// 66.434 us; speedup vs baseline: 1.1289x; 1.1289x over previous
//
#include <hip/hip_runtime.h>

typedef unsigned short u16;
typedef unsigned int u32;
typedef __attribute__((ext_vector_type(8))) __bf16 bf16x8;
typedef __attribute__((ext_vector_type(4))) float f32x4;

// RK2 midpoint, single step h = 1:  k1=f(z); k2=f(z + k1/2); y = z + k2
// tanh input pre-scale folded into GEMM1-path weights: acc = 2*log2(e)*(zu@W1+b1)
constexpr float TSC = 2.885390081777927f;   // 2*log2(e)

// weight regions, u16 units. All A-frags 16x16x32: lane l holds
// A[m = base+(l&15)][k = kc*32 + (l>>4)*8 + e].
// Global K layout: z(64) | u(16) 1(1) pad(15) | H(...)
#define OFF_WG1   0        // [16 ct][3 kc]  f: W1 (K=96: z|u|b1-ones)   (24576)
#define OFF_WG2   24576    // [4 ct][11 kc]  f: A^T,c2-ones,W2 (K=352)   (22528)
#define OFF_WH1   47104    // [8 ct][3 kc]   head L1 (K=96)              (12288)
#define OFF_WH2   59392    // [2 ot][5 kc]   head L2 (K=128 H | ob2-ones)(5120)
#define W_TOTAL   64512

// X2 row stride (elems): padded linear. 328*2B = 656 B -> row r starts at
// bank 4r mod 32; all LDS addresses fold to base + compile-time immediates.
#define XS 328

__device__ __forceinline__ u16 f2bf(float f) {
  __bf16 h = (__bf16)f;
  return __builtin_bit_cast(u16, h);
}
__device__ __forceinline__ u32 pk2(float a, float b) {
  return (u32)f2bf(a) | ((u32)f2bf(b) << 16);
}
// input already scaled by 2*log2(e): tanh = 1 - 2/(2^x + 1)
__device__ __forceinline__ float tanh_pre(float x) {
#if __has_builtin(__builtin_amdgcn_exp2f)
  float e = __builtin_amdgcn_exp2f(x);
#else
  float e = exp2f(x);
#endif
  return 1.0f - 2.0f * __builtin_amdgcn_rcpf(e + 1.0f);
}

// ---------------- setup: pack weights as 16x16x32 A-frags --------------------
__global__ void setup_kernel(const float* __restrict__ L,
  const float* __restrict__ aw1, const float* __restrict__ ab1,
  const float* __restrict__ aw2, const float* __restrict__ ab2,
  const float* __restrict__ rw1, const float* __restrict__ rb1,
  const float* __restrict__ rw2, const float* __restrict__ rb2,
  const float* __restrict__ ow1, const float* __restrict__ ob1,
  const float* __restrict__ ow2, const float* __restrict__ ob2,
  u16* __restrict__ W)
{
  const int gid = blockIdx.x * blockDim.x + threadIdx.x;
  const int gstr = gridDim.x * blockDim.x;
  for (int i = gid; i < W_TOTAL; i += gstr) {
    float v;
    if (i < 24576) {                 // Wg1: hidden 256 x K=96, TSC-scaled
      const int j = i, e = j & 7, l = (j >> 3) & 63, f = j >> 9;
      const int ct = f / 3, kc = f - ct * 3;
      const int m = ct * 16 + (l & 15);
      const int k = kc * 32 + ((l >> 4) << 3) + e;
      if (k < 64)       v = TSC * ((m < 128) ? aw1[m * 80 + k] : rw1[(m - 128) * 80 + k]);
      else if (k < 80)  v = TSC * ((m < 128) ? aw1[m * 80 + 64 + (k - 64)]
                                             : rw1[(m - 128) * 80 + 64 + (k - 64)]);
      else if (k == 80) v = TSC * ((m < 128) ? ab1[m] : rb1[m - 128]);
      else              v = 0.0f;
    } else if (i < 47104) {          // Wg2: lat 64 x K=352 (z:A^T | c2-ones | H:w2)
      const int j = i - 24576, e = j & 7, l = (j >> 3) & 63, f = j >> 9;
      const int ct = f / 11, kc = f - ct * 11;
      const int m = ct * 16 + (l & 15);
      const int k = kc * 32 + ((l >> 4) << 3) + e;
      if (k < 64) {                  // A = -(L L^T), symmetric
        float s = 0.0f;
        for (int q = 0; q < 64; ++q) s += L[m * 64 + q] * L[k * 64 + q];
        v = -s;
      } else if (k == 80) v = ab2[m] + rb2[m];
      else if (k < 96)    v = 0.0f;
      else {
        const int h = k - 96;
        v = (h < 128) ? aw2[m * 128 + h] : rw2[m * 128 + (h - 128)];
      }
    } else if (i < 59392) {          // Wh1: head hidden 128 x K=96 (unscaled)
      const int j = i - 47104, e = j & 7, l = (j >> 3) & 63, f = j >> 9;
      const int ct = f / 3, kc = f - ct * 3;
      const int m = ct * 16 + (l & 15);
      const int k = kc * 32 + ((l >> 4) << 3) + e;
      if (k < 64)       v = ow1[m * 80 + k];
      else if (k < 80)  v = ow1[m * 80 + 64 + (k - 64)];
      else if (k == 80) v = ob1[m];
      else              v = 0.0f;
    } else {                         // Wh2: out 32(pad of 20) x K=160 (H | ob2-ones)
      const int j = i - 59392, e = j & 7, l = (j >> 3) & 63, f = j >> 9;
      const int ot = f / 5, kc = f - ot * 5;
      const int m = ot * 16 + (l & 15);
      const int k = kc * 32 + ((l >> 4) << 3) + e;
      if (m >= 20)       v = 0.0f;
      else if (k < 128)  v = ow2[m * 128 + k];
      else if (k == 144) v = ob2[m];
      else               v = 0.0f;
    }
    W[i] = f2bf(v);
  }
}

// ---------------- fused: RK2 step (2 fevals) + head ---------------------------
// R21 = R18 (champion, V=52, 67.3us) with the occupancy target raised via
// amdgpu_waves_per_eu(4,4): budget 512/4 = 128 >> demand (~52), so no spill
// squeeze is expected (unlike R7, whose demand ~130 exceeded the budget).
// Goal: lift residency from 3 to 4 waves/EU.
__global__ __attribute__((amdgpu_flat_work_group_size(256, 256), amdgpu_waves_per_eu(4, 4)))
void fused_kernel(
    const float* __restrict__ zt, const float* __restrict__ ut,
    const u16* __restrict__ W,
    float* __restrict__ outz, float* __restrict__ outy)
{
  __shared__ __align__(16) u16 X2[32 * XS];    // [z(64)|u-gap|H(256)] bf16
  __shared__ const u16* WpS;                   // opaque weight base (anti-LICM)
  const int tid = threadIdx.x, w = tid >> 6, l = tid & 63, li = l & 15, h4 = l >> 4;
  const int R0 = blockIdx.x * 32;
  const int latb = w * 16 + 4 * h4;            // owned 4 lat cols

  if (tid == 0) WpS = W;

  // per-thread LDS bases (elems)
  const int rb0 = li * XS;                     // row li
  const int rb1b = (16 + li) * XS;             // row 16+li

  // ---- stage X2 z (full tile, thread-strided) ----
  {
    const int r = tid >> 3, c0 = (tid & 7) * 8;
    const float4 za = *(const float4*)&zt[(size_t)(R0 + r) * 64 + c0];
    const float4 zb = *(const float4*)&zt[(size_t)(R0 + r) * 64 + c0 + 4];
    *(uint4*)&X2[r * XS + c0] =
        make_uint4(pk2(za.x, za.y), pk2(za.z, za.w), pk2(zb.x, zb.y), pk2(zb.z, zb.w));
  }
  // ---- z8 state (owned positions) ----
  float z8[8];
  {
    const float4 a = *(const float4*)&zt[(size_t)(R0 + li) * 64 + latb];
    const float4 b = *(const float4*)&zt[(size_t)(R0 + 16 + li) * 64 + latb];
    z8[0] = a.x; z8[1] = a.y; z8[2] = a.z; z8[3] = a.w;
    z8[4] = b.x; z8[5] = b.y; z8[6] = b.z; z8[7] = b.w;
  }
  // ---- bu[rt]: resident B-frags holding u(16)|1|pad for K-slice 64..95 ----
  bf16x8 bu[2];
  #pragma unroll
  for (int rt = 0; rt < 2; ++rt) {
    union { bf16x8 v; uint4 u; } t;
    if (h4 < 2) {
      const float4 ua = *(const float4*)&ut[(size_t)(R0 + rt * 16 + li) * 16 + h4 * 8];
      const float4 ub = *(const float4*)&ut[(size_t)(R0 + rt * 16 + li) * 16 + h4 * 8 + 4];
      t.u = make_uint4(pk2(ua.x, ua.y), pk2(ua.z, ua.w), pk2(ub.x, ub.y), pk2(ub.z, ub.w));
    } else if (h4 == 2) {
      t.u = make_uint4(0x3F80u, 0u, 0u, 0u);   // {1, 0, ...} at k_local 16 (k=80)
    } else {
      t.u = make_uint4(0u, 0u, 0u, 0u);
    }
    bu[rt] = t.v;
  }

  float kp8[8];

  auto feval = [&]() {
    __syncthreads();                          // zi (+WpS first time) visible
    const u16* Wp = WpS;                      // opaque: reload weights each call
    // GEMM1: H = tanh(z@W1z + u@W1u + b1). z-frags live ONLY in this section.
    {
      bf16x8 bz[2][2];
      #pragma unroll
      for (int rt = 0; rt < 2; ++rt) {
        const int rb = rt ? rb1b : rb0;
        bz[rt][0] = *(const bf16x8*)&X2[rb + h4 * 8];
        bz[rt][1] = *(const bf16x8*)&X2[rb + 32 + h4 * 8];
      }
      #pragma unroll
      for (int ct = 0; ct < 4; ++ct) {
        const int cg = w * 4 + ct;
        const bf16x8 w0 = *(const bf16x8*)(Wp + OFF_WG1 + ((cg * 3 + 0) * 64 + l) * 8);
        const bf16x8 w1 = *(const bf16x8*)(Wp + OFF_WG1 + ((cg * 3 + 1) * 64 + l) * 8);
        const bf16x8 w2 = *(const bf16x8*)(Wp + OFF_WG1 + ((cg * 3 + 2) * 64 + l) * 8);
        const int hcb = 64 + cg * 16 + 4 * h4;
        #pragma unroll
        for (int rt = 0; rt < 2; ++rt) {
          f32x4 acc = {0.0f, 0.0f, 0.0f, 0.0f};
          acc = __builtin_amdgcn_mfma_f32_16x16x32_bf16(w0, bz[rt][0], acc, 0, 0, 0);
          acc = __builtin_amdgcn_mfma_f32_16x16x32_bf16(w1, bz[rt][1], acc, 0, 0, 0);
          acc = __builtin_amdgcn_mfma_f32_16x16x32_bf16(w2, bu[rt],   acc, 0, 0, 0);
          const float t0 = tanh_pre(acc[0]), t1 = tanh_pre(acc[1]);
          const float t2 = tanh_pre(acc[2]), t3 = tanh_pre(acc[3]);
          *(uint2*)&X2[(rt ? rb1b : rb0) + hcb] = make_uint2(pk2(t0, t1), pk2(t2, t3));
        }
      }
    }
    __syncthreads();                          // H visible
    // GEMM2: k = z@A^T + c2 + H@W2^T  (K=352; single chain per rt, 2 indep
    // chains via rt interleave). z/u frags re-read from LDS (region unchanged).
    f32x4 acc2[2] = {{0.0f, 0.0f, 0.0f, 0.0f}, {0.0f, 0.0f, 0.0f, 0.0f}};
    #pragma unroll
    for (int kc = 0; kc < 11; ++kc) {
      const bf16x8 wk = *(const bf16x8*)(Wp + OFF_WG2 + ((w * 11 + kc) * 64 + l) * 8);
      #pragma unroll
      for (int rt = 0; rt < 2; ++rt) {
        bf16x8 bf;
        if (kc == 2) {
          bf = bu[rt];
        } else {
          const int col = (kc < 2) ? kc * 32 : 64 + (kc - 3) * 32;
          bf = *(const bf16x8*)&X2[(rt ? rb1b : rb0) + col + h4 * 8];
        }
        acc2[rt] = __builtin_amdgcn_mfma_f32_16x16x32_bf16(wk, bf, acc2[rt], 0, 0, 0);
      }
    }
    #pragma unroll
    for (int rt = 0; rt < 2; ++rt)
      #pragma unroll
      for (int r = 0; r < 4; ++r) kp8[rt * 4 + r] = acc2[rt][r];
  };

  auto stzi = [&](const float* v) {
    *(uint2*)&X2[rb0 + latb]  = make_uint2(pk2(v[0], v[1]), pk2(v[2], v[3]));
    *(uint2*)&X2[rb1b + latb] = make_uint2(pk2(v[4], v[5]), pk2(v[6], v[7]));
  };

  // RK2 midpoint; weights reloaded per iteration (unroll 1 keeps them dead)
  #pragma unroll 1
  for (int s = 0; s < 2; ++s) {
    feval();
    if (s == 0) {
      #pragma unroll
      for (int i = 0; i < 8; ++i) kp8[i] = z8[i] + 0.5f * kp8[i];
      stzi(kp8);
    }
  }
  #pragma unroll
  for (int i = 0; i < 8; ++i) z8[i] += kp8[i];
  stzi(z8);                                    // z_final -> X2 (bf16) for head
  // zt1 out (f32 from regs)
  *(float4*)&outz[(size_t)(R0 + li) * 64 + latb]      = make_float4(z8[0], z8[1], z8[2], z8[3]);
  *(float4*)&outz[(size_t)(R0 + 16 + li) * 64 + latb] = make_float4(z8[4], z8[5], z8[6], z8[7]);

  // ---------------- output head ----------------
  __syncthreads();                             // z_final visible; k2 reads done
  {
    const u16* Wp = WpS;
    bf16x8 bzf[2][2];
    #pragma unroll
    for (int rt = 0; rt < 2; ++rt) {
      const int rb = rt ? rb1b : rb0;
      bzf[rt][0] = *(const bf16x8*)&X2[rb + h4 * 8];
      bzf[rt][1] = *(const bf16x8*)&X2[rb + 32 + h4 * 8];
    }
    // head GEMM1: relu(z@Wh1 + u@Wh1u + ob1) -> X2 H cols [64,192)
    #pragma unroll
    for (int j2 = 0; j2 < 2; ++j2) {
      const int cg = w * 2 + j2;
      const bf16x8 w0 = *(const bf16x8*)(Wp + OFF_WH1 + ((cg * 3 + 0) * 64 + l) * 8);
      const bf16x8 w1 = *(const bf16x8*)(Wp + OFF_WH1 + ((cg * 3 + 1) * 64 + l) * 8);
      const bf16x8 w2 = *(const bf16x8*)(Wp + OFF_WH1 + ((cg * 3 + 2) * 64 + l) * 8);
      const int hcb = 64 + cg * 16 + 4 * h4;
      #pragma unroll
      for (int rt = 0; rt < 2; ++rt) {
        f32x4 acc = {0.0f, 0.0f, 0.0f, 0.0f};
        acc = __builtin_amdgcn_mfma_f32_16x16x32_bf16(w0, bzf[rt][0], acc, 0, 0, 0);
        acc = __builtin_amdgcn_mfma_f32_16x16x32_bf16(w1, bzf[rt][1], acc, 0, 0, 0);
        acc = __builtin_amdgcn_mfma_f32_16x16x32_bf16(w2, bu[rt],    acc, 0, 0, 0);
        const float e0 = fmaxf(acc[0], 0.0f), e1 = fmaxf(acc[1], 0.0f);
        const float e2 = fmaxf(acc[2], 0.0f), e3 = fmaxf(acc[3], 0.0f);
        *(uint2*)&X2[(rt ? rb1b : rb0) + hcb] = make_uint2(pk2(e0, e1), pk2(e2, e3));
      }
    }
  }
  __syncthreads();
  // head GEMM2: waves 0,1 -> 20 output cols (pad 32); bias via bu ones-col
  if (w < 2) {
    const u16* Wp = WpS;
    const int ocb = w * 16 + 4 * h4;
    f32x4 acco[2] = {{0.0f, 0.0f, 0.0f, 0.0f}, {0.0f, 0.0f, 0.0f, 0.0f}};
    #pragma unroll
    for (int kc = 0; kc < 4; ++kc) {
      const bf16x8 wk = *(const bf16x8*)(Wp + OFF_WH2 + ((w * 5 + kc) * 64 + l) * 8);
      #pragma unroll
      for (int rt = 0; rt < 2; ++rt) {
        const bf16x8 bh = *(const bf16x8*)&X2[(rt ? rb1b : rb0) + 64 + kc * 32 + h4 * 8];
        acco[rt] = __builtin_amdgcn_mfma_f32_16x16x32_bf16(wk, bh, acco[rt], 0, 0, 0);
      }
    }
    {
      const bf16x8 wb = *(const bf16x8*)(Wp + OFF_WH2 + ((w * 5 + 4) * 64 + l) * 8);
      #pragma unroll
      for (int rt = 0; rt < 2; ++rt)
        acco[rt] = __builtin_amdgcn_mfma_f32_16x16x32_bf16(wb, bu[rt], acco[rt], 0, 0, 0);
    }
    if (ocb < 20) {
      *(float4*)&outy[(size_t)(R0 + li) * 20 + ocb] =
          make_float4(acco[0][0], acco[0][1], acco[0][2], acco[0][3]);
      *(float4*)&outy[(size_t)(R0 + 16 + li) * 20 + ocb] =
          make_float4(acco[1][0], acco[1][1], acco[1][2], acco[1][3]);
    }
  }
}

extern "C" void kernel_launch(void* const* d_in, const int* in_sizes, int n_in,
                              void* d_out, int out_size, void* d_ws, size_t ws_size,
                              hipStream_t stream) {
  const float* zt  = (const float*)d_in[0];
  const float* ut  = (const float*)d_in[2];
  const float* L   = (const float*)d_in[3];
  const float* aw1 = (const float*)d_in[4];
  const float* ab1 = (const float*)d_in[5];
  const float* aw2 = (const float*)d_in[6];
  const float* ab2 = (const float*)d_in[7];
  const float* rw1 = (const float*)d_in[8];
  const float* rb1 = (const float*)d_in[9];
  const float* rw2 = (const float*)d_in[10];
  const float* rb2 = (const float*)d_in[11];
  const float* ow1 = (const float*)d_in[12];
  const float* ob1 = (const float*)d_in[13];
  const float* ow2 = (const float*)d_in[14];
  const float* ob2 = (const float*)d_in[15];

  u16* W = (u16*)d_ws;
  float* outz = (float*)d_out;
  float* outy = outz + (size_t)131072 * 64;

  hipLaunchKernelGGL(setup_kernel, dim3(64), dim3(256), 0, stream,
      L, aw1, ab1, aw2, ab2, rw1, rb1, rw2, rb2, ow1, ob1, ow2, ob2, W);
  hipLaunchKernelGGL(fused_kernel, dim3(4096), dim3(256), 0, stream,
      zt, ut, W, outz, outy);
}